// Round 3
// baseline (168.407 us; speedup 1.0000x reference)
//
#include <hip/hip_runtime.h>
#include <hip/hip_bf16.h>
#include <cmath>
#include <complex>

// Problem constants
constexpr int TT  = 50;            // time length
constexpr int NB  = 50;            // batch
constexpr int NC  = 4096;          // channels
constexpr int NCH = NB * NC;       // 204800 independent series
constexpr int PAD = 49;
constexpr int EXT = TT + 2 * PAD;  // 148
constexpr int CT  = 16;            // channel tile per block (block = CT x NB threads)

struct Coefs {
    double b0[2][2], b1[2][2], b2[2][2], a1[2][2], a2[2][2];
    double zi0[2][2], zi1[2][2];
};

// ---------------- Setup kernel: build the 50x50 filtfilt+demean matrix per band ----
// Mt[(band*TT + k)*TT + t] = d y[t] / d x[k]  (y demeaned over t), double precision.
// One block per band, thread j = basis column. State lives in REGISTERS (fully
// unrolled e[148] doubles, ~330 VGPR at 1 wave/SIMD — only 2 blocks exist, so
// occupancy is irrelevant; what matters is the ~20 cyc/step dependent chain instead
// of the ~120 cyc LDS round-trip that cost ~95 us last round).
__global__ void __launch_bounds__(64, 1) build_M(float* __restrict__ Mt, Coefs cf) {
    const int band = blockIdx.x;
    const int j = threadIdx.x;
    if (j >= TT) return;

    double e[EXT];
    // odd extension of basis vector e_j
#pragma unroll
    for (int i = 0; i < PAD; ++i)
        e[i] = 2.0 * (j == 0 ? 1.0 : 0.0) - ((PAD - i) == j ? 1.0 : 0.0);
#pragma unroll
    for (int t = 0; t < TT; ++t) e[PAD + t] = (t == j) ? 1.0 : 0.0;
#pragma unroll
    for (int i = 0; i < PAD; ++i)
        e[PAD + TT + i] = 2.0 * (j == TT - 1 ? 1.0 : 0.0) - ((TT - 2 - i) == j ? 1.0 : 0.0);

    const double x0 = e[0];
#pragma unroll
    for (int s = 0; s < 2; ++s) {
        const double b0 = cf.b0[band][s], b1 = cf.b1[band][s], b2 = cf.b2[band][s];
        const double a1 = cf.a1[band][s], a2 = cf.a2[band][s];
        double z0 = cf.zi0[band][s] * x0, z1 = cf.zi1[band][s] * x0;
#pragma unroll
        for (int i = 0; i < EXT; ++i) {
            const double xt = e[i];
            const double yt = b0 * xt + z0;
            z0 = b1 * xt + z1 - a1 * yt;
            z1 = b2 * xt - a2 * yt;
            e[i] = yt;
        }
    }
    const double y0 = e[EXT - 1];
#pragma unroll
    for (int s = 0; s < 2; ++s) {
        const double b0 = cf.b0[band][s], b1 = cf.b1[band][s], b2 = cf.b2[band][s];
        const double a1 = cf.a1[band][s], a2 = cf.a2[band][s];
        double z0 = cf.zi0[band][s] * y0, z1 = cf.zi1[band][s] * y0;
#pragma unroll
        for (int m = 0; m < EXT; ++m) {
            const int i = EXT - 1 - m;
            const double xt = e[i];
            const double yt = b0 * xt + z0;
            z0 = b1 * xt + z1 - a1 * yt;
            z1 = b2 * xt - a2 * yt;
            e[i] = yt;
        }
    }
    // slice [PAD, PAD+TT) and fold the demean over t
    double mean = 0.0;
#pragma unroll
    for (int t = 0; t < TT; ++t) mean += e[PAD + t];
    mean *= (1.0 / TT);
#pragma unroll
    for (int t = 0; t < TT; ++t)
        Mt[(band * TT + j) * TT + t] = (float)(e[PAD + t] - mean);
}

// ---------------- Main kernel -------------------------------------------------------
// Block = (CT=16 channels) x (all 50 batches); wave = 16c x 4b -> four 64-B segments
// per load, fully-used cache lines. BOTH bands fused: x read from HBM once.
// k-loop FULLY UNROLLED to straight-line code so the compiler cannot interchange
// loops or shrink the accumulator file (round 2 showed VGPR=36 => it rematerialized
// x[k] per t, ~2 TB of L1 traffic, 54 us L1-bound). 100 accumulators + in-flight
// loads ~ 120 VGPR, capped at 128 by __launch_bounds__(800,4).
// Normalization quirk (T==B==50): out[t,b,c] = (y[t,b,c] - mu[t,c]) * inv[t,c] --
// stats indexed by TIME t, i.e. the stats of batch-row t. Exchanged through LDS.
__global__ void __launch_bounds__(CT * NB, 4)
filt_main(const float* __restrict__ x, const float* __restrict__ Mt,
          float* __restrict__ out) {
    const int tx = threadIdx.x;                 // channel within tile
    const int b  = threadIdx.y;                 // batch
    const int c  = blockIdx.x * CT + tx;
    const int i  = b * NC + c;

    __shared__ float smu0[NB][CT], sinv0[NB][CT];
    __shared__ float smu1[NB][CT], sinv1[NB][CT];

    float f0[TT], f1[TT];
#pragma unroll
    for (int t = 0; t < TT; ++t) { f0[t] = 0.f; f1[t] = 0.f; }

    const float* __restrict__ M0 = Mt;            // band 0, [k][t]
    const float* __restrict__ M1 = Mt + TT * TT;  // band 1

#pragma unroll
    for (int k = 0; k < TT; ++k) {
        const float xk = x[(size_t)k * NCH + i];  // coalesced; straight-line => hoisted
#pragma unroll
        for (int t = 0; t < TT; ++t) {
            f0[t] = fmaf(M0[k * TT + t], xk, f0[t]);   // wave-uniform -> s_load
            f1[t] = fmaf(M1[k * TT + t], xk, f1[t]);
        }
    }

    // per-(b,c) stats, both bands
    float mu0 = 0.f, mu1 = 0.f;
#pragma unroll
    for (int t = 0; t < TT; ++t) { mu0 += f0[t]; mu1 += f1[t]; }
    mu0 *= (1.0f / TT); mu1 *= (1.0f / TT);
    float ss0 = 0.f, ss1 = 0.f;
#pragma unroll
    for (int t = 0; t < TT; ++t) {
        const float h0 = f0[t] - mu0; ss0 = fmaf(h0, h0, ss0);
        const float h1 = f1[t] - mu1; ss1 = fmaf(h1, h1, ss1);
    }
    smu0[b][tx] = mu0; sinv0[b][tx] = 1.0f / sqrtf(ss0 * (1.0f / (TT - 1)));
    smu1[b][tx] = mu1; sinv1[b][tx] = 1.0f / sqrtf(ss1 * (1.0f / (TT - 1)));
    __syncthreads();

#pragma unroll
    for (int t = 0; t < TT; ++t) {
        out[(size_t)t * NCH + i] =
            (f0[t] - smu0[t][tx]) * sinv0[t][tx];                 // QUIRK: [t], not [b]
        out[(size_t)(TT + t) * NCH + i] =
            (f1[t] - smu1[t][tx]) * sinv1[t][tx];
    }
}

// ---------------- Host: Butterworth bandpass SOS + zi (reference-exact, double) ----
static Coefs make_coefs() {
    Coefs cf;
    const double bands[2][2] = {{0.05, 0.15}, {0.2, 0.4}};
    const int n = 2;  // ORDER
    for (int bd = 0; bd < 2; ++bd) {
        const double fs = 2.0;
        const double w1 = bands[bd][0], w2 = bands[bd][1];
        const double warped0 = 2.0 * fs * std::tan(M_PI * w1 / fs);
        const double warped1 = 2.0 * fs * std::tan(M_PI * w2 / fs);
        const double bw = warped1 - warped0;
        const double wo = std::sqrt(warped0 * warped1);
        std::complex<double> p_bp[4];
        for (int k = 1; k <= n; ++k) {
            std::complex<double> p = -std::exp(std::complex<double>(0.0, M_PI * (2 * k - 1) / (2.0 * n)));
            std::complex<double> plp = p * (bw / 2.0);
            std::complex<double> disc = std::sqrt(plp * plp - std::complex<double>(wo * wo, 0.0));
            p_bp[k - 1] = plp + disc;
            p_bp[n + k - 1] = plp - disc;
        }
        const double fs2 = 2.0 * fs;
        std::complex<double> prod(1.0, 0.0);
        for (int i = 0; i < 2 * n; ++i) prod *= (fs2 - p_bp[i]);
        const double gain = std::pow(bw, n) * std::pow(fs2, n) / prod.real();
        std::complex<double> p_d[4];
        for (int i = 0; i < 2 * n; ++i) p_d[i] = (fs2 + p_bp[i]) / (fs2 - p_bp[i]);
        double sos[2][6];
        int cnt = 0;
        for (int i = 0; i < 2 * n; ++i) {
            if (p_d[i].imag() > 0) {
                const double g = (cnt == 0) ? gain : 1.0;
                sos[cnt][0] = g;
                sos[cnt][1] = 0.0;
                sos[cnt][2] = -g;
                sos[cnt][3] = 1.0;
                sos[cnt][4] = -2.0 * p_d[i].real();
                sos[cnt][5] = std::norm(p_d[i]);
                ++cnt;
            }
        }
        double scale = 1.0;
        for (int s = 0; s < 2; ++s) {
            const double b0 = sos[s][0], b1 = sos[s][1], b2 = sos[s][2];
            const double a1 = sos[s][4], a2 = sos[s][5];
            const double B0 = b1 - a1 * b0, B1 = b2 - a2 * b0;
            const double det = 1.0 + a1 + a2;
            cf.b0[bd][s] = b0; cf.b1[bd][s] = b1; cf.b2[bd][s] = b2;
            cf.a1[bd][s] = a1; cf.a2[bd][s] = a2;
            cf.zi0[bd][s] = scale * (B0 + B1) / det;
            cf.zi1[bd][s] = scale * ((1.0 + a1) * B1 - a2 * B0) / det;
            scale *= (b0 + b1 + b2) / (1.0 + a1 + a2);
        }
    }
    return cf;
}

extern "C" void kernel_launch(void* const* d_in, const int* in_sizes, int n_in,
                              void* d_out, int out_size, void* d_ws, size_t ws_size,
                              hipStream_t stream) {
    const float* x = (const float*)d_in[0];
    float* out = (float*)d_out;
    float* Mt = (float*)d_ws;  // 2*50*50 floats = 20 KB

    const Coefs cf = make_coefs();
    build_M<<<dim3(2), dim3(64), 0, stream>>>(Mt, cf);
    filt_main<<<dim3(NC / CT), dim3(CT, NB), 0, stream>>>(x, Mt, out);
}

// Round 4
// 159.777 us; speedup vs baseline: 1.0540x; 1.0540x over previous
//
#include <hip/hip_runtime.h>
#include <hip/hip_bf16.h>
#include <cmath>
#include <complex>

// Problem constants
constexpr int TT  = 50;            // time length
constexpr int NB  = 50;            // batch
constexpr int NC  = 4096;          // channels
constexpr int NCH = NB * NC;       // 204800 independent series
constexpr int PAD = 49;
constexpr int EXT = TT + 2 * PAD;  // 148
constexpr int CT  = 16;            // channel tile per block (block = CT x NB threads)

struct Coefs {
    double b0[2][2], b1[2][2], b2[2][2], a1[2][2], a2[2][2];
    double zi0[2][2], zi1[2][2];
};

// ---------------- Setup kernel: build the 50x50 filtfilt+demean matrix per band ----
// Mt[(band*TT + j)*TT + t] = d y[t] / d x[j]  (y demeaned over t).
// One block per band, thread j = basis column. The two biquad sections are fused
// ELEMENTWISE (exact for a cascade), so the forward pass only WRITES the filtered
// sequence to LDS and the backward pass only READS it -- no scratch array, no LDS
// round-trip inside the dependent chain (round 3's e[148] went to scratch via SROA
// failure: ~150 cyc/step * 592 steps = 84 us). States live in 8 fp64 registers;
// only the 50 sliced outputs are kept (float o[50], SROA-safe).
__global__ void __launch_bounds__(64, 1) build_M(float* __restrict__ Mt, Coefs cf) {
    __shared__ float ylds[EXT][TT];   // 148*50*4 = 29.6 KB; column j private to thread j
    const int band = blockIdx.x;
    const int j = threadIdx.x;
    if (j >= TT) return;

    const double b00 = cf.b0[band][0], b10 = cf.b1[band][0], b20 = cf.b2[band][0];
    const double a10 = cf.a1[band][0], a20 = cf.a2[band][0];
    const double b01 = cf.b0[band][1], b11 = cf.b1[band][1], b21 = cf.b2[band][1];
    const double a11 = cf.a1[band][1], a21 = cf.a2[band][1];

    // x0 = ext[0] = 2*delta(j,0) - delta(j,PAD)
    const double x0 = 2.0 * (j == 0 ? 1.0 : 0.0) - (j == PAD ? 1.0 : 0.0);

    // ---- forward pass (both sections fused, write-only to LDS) ----
    double s00 = cf.zi0[band][0] * x0, s01 = cf.zi1[band][0] * x0;
    double s10 = cf.zi0[band][1] * x0, s11 = cf.zi1[band][1] * x0;
    double ylast = 0.0;
#pragma unroll
    for (int i = 0; i < EXT; ++i) {
        double xt;
        if (i < PAD)            xt = 2.0 * (j == 0 ? 1.0 : 0.0) - (j == PAD - i ? 1.0 : 0.0);
        else if (i < PAD + TT)  xt = (j == i - PAD) ? 1.0 : 0.0;
        else                    xt = 2.0 * (j == TT - 1 ? 1.0 : 0.0)
                                     - (j == 2 * TT - 2 - (i - PAD) ? 1.0 : 0.0);
        const double y0 = b00 * xt + s00;
        s00 = b10 * xt + s01 - a10 * y0;
        s01 = b20 * xt - a20 * y0;
        const double y1 = b01 * y0 + s10;
        s10 = b11 * y0 + s11 - a11 * y1;
        s11 = b21 * y0 - a21 * y1;
        ylds[i][j] = (float)y1;
        if (i == EXT - 1) ylast = y1;
    }

    // ---- backward pass (read-only from LDS, keep only the slice [PAD, PAD+TT)) ----
    s00 = cf.zi0[band][0] * ylast; s01 = cf.zi1[band][0] * ylast;
    s10 = cf.zi0[band][1] * ylast; s11 = cf.zi1[band][1] * ylast;
    float o[TT];
#pragma unroll
    for (int m = 0; m < EXT; ++m) {
        const int i = EXT - 1 - m;              // process reversed; result is un-reversed
        const double xt = (double)ylds[i][j];
        const double y0 = b00 * xt + s00;
        s00 = b10 * xt + s01 - a10 * y0;
        s01 = b20 * xt - a20 * y0;
        const double y1 = b01 * y0 + s10;
        s10 = b11 * y0 + s11 - a11 * y1;
        s11 = b21 * y0 - a21 * y1;
        if (i >= PAD && i < PAD + TT) o[i - PAD] = (float)y1;
    }

    // fold the demean over t, store column j
    float mean = 0.f;
#pragma unroll
    for (int t = 0; t < TT; ++t) mean += o[t];
    mean *= (1.0f / TT);
#pragma unroll
    for (int t = 0; t < TT; ++t)
        Mt[(band * TT + j) * TT + t] = o[t] - mean;
}

// ---------------- Main kernel -------------------------------------------------------
// Block = (CT=16 channels) x (all 50 batches) = 800 threads = 13 waves.
// A 13-wave block REQUIRES VGPR <= 128 (one SIMD hosts 4 waves). So bands are
// processed SEQUENTIALLY (50 accums each, ~110 VGPR total) -- the block's x-tile is
// 50*16*4 B = 3.2 KB, L1-resident, so band 1's re-read never touches HBM.
// __launch_bounds__(800,3): 13 waves = 3.25/EU >= 3 -> compiler provisions 1
// block/CU, VGPR cap 128. (Round 3's (800,4) forced 2 blocks/CU -> VGPR 64 ->
// spills -> +57 MB scratch WRITE and 82 us.)
// k-loop fully unrolled: straight-line code, no interchange (round 2: VGPR 36,
// x rematerialized 50x -> 2 TB of L1 traffic).
// Normalization quirk (T==B==50): out[t,b,c] = (y[t,b,c] - mu[t,c]) * inv[t,c] --
// stats indexed by TIME t (the stats of batch-row t), exchanged through LDS.
__global__ void __launch_bounds__(CT * NB, 3)
filt_main(const float* __restrict__ x, const float* __restrict__ Mt,
          float* __restrict__ out) {
    const int tx = threadIdx.x;                 // channel within tile
    const int b  = threadIdx.y;                 // batch
    const int c  = blockIdx.x * CT + tx;
    const int i  = b * NC + c;

    __shared__ float smu[NB][CT], sinv[NB][CT];

#pragma unroll 1
    for (int band = 0; band < 2; ++band) {
        const float* __restrict__ Mb = Mt + band * TT * TT;   // wave-uniform -> s_load
        float f[TT];
#pragma unroll
        for (int t = 0; t < TT; ++t) f[t] = 0.f;

#pragma unroll
        for (int k = 0; k < TT; ++k) {
            const float xk = x[(size_t)k * NCH + i];          // coalesced; L1-hit on band 1
#pragma unroll
            for (int t = 0; t < TT; ++t) f[t] = fmaf(Mb[k * TT + t], xk, f[t]);
        }

        // per-(b,c) stats (ddof=1), publish to LDS
        float mu = 0.f;
#pragma unroll
        for (int t = 0; t < TT; ++t) mu += f[t];
        mu *= (1.0f / TT);
        float ss = 0.f;
#pragma unroll
        for (int t = 0; t < TT; ++t) {
            const float h = f[t] - mu;
            ss = fmaf(h, h, ss);
        }
        smu[b][tx] = mu;
        sinv[b][tx] = 1.0f / sqrtf(ss * (1.0f / (TT - 1)));
        __syncthreads();

#pragma unroll
        for (int t = 0; t < TT; ++t)
            out[(size_t)(band * TT + t) * NCH + i] =
                (f[t] - smu[t][tx]) * sinv[t][tx];            // QUIRK: [t], not [b]
        __syncthreads();   // protect LDS stats before next band overwrites
    }
}

// ---------------- Host: Butterworth bandpass SOS + zi (reference-exact, double) ----
static Coefs make_coefs() {
    Coefs cf;
    const double bands[2][2] = {{0.05, 0.15}, {0.2, 0.4}};
    const int n = 2;  // ORDER
    for (int bd = 0; bd < 2; ++bd) {
        const double fs = 2.0;
        const double w1 = bands[bd][0], w2 = bands[bd][1];
        const double warped0 = 2.0 * fs * std::tan(M_PI * w1 / fs);
        const double warped1 = 2.0 * fs * std::tan(M_PI * w2 / fs);
        const double bw = warped1 - warped0;
        const double wo = std::sqrt(warped0 * warped1);
        std::complex<double> p_bp[4];
        for (int k = 1; k <= n; ++k) {
            std::complex<double> p = -std::exp(std::complex<double>(0.0, M_PI * (2 * k - 1) / (2.0 * n)));
            std::complex<double> plp = p * (bw / 2.0);
            std::complex<double> disc = std::sqrt(plp * plp - std::complex<double>(wo * wo, 0.0));
            p_bp[k - 1] = plp + disc;
            p_bp[n + k - 1] = plp - disc;
        }
        const double fs2 = 2.0 * fs;
        std::complex<double> prod(1.0, 0.0);
        for (int i = 0; i < 2 * n; ++i) prod *= (fs2 - p_bp[i]);
        const double gain = std::pow(bw, n) * std::pow(fs2, n) / prod.real();
        std::complex<double> p_d[4];
        for (int i = 0; i < 2 * n; ++i) p_d[i] = (fs2 + p_bp[i]) / (fs2 - p_bp[i]);
        double sos[2][6];
        int cnt = 0;
        for (int i = 0; i < 2 * n; ++i) {
            if (p_d[i].imag() > 0) {
                const double g = (cnt == 0) ? gain : 1.0;
                sos[cnt][0] = g;
                sos[cnt][1] = 0.0;
                sos[cnt][2] = -g;
                sos[cnt][3] = 1.0;
                sos[cnt][4] = -2.0 * p_d[i].real();
                sos[cnt][5] = std::norm(p_d[i]);
                ++cnt;
            }
        }
        double scale = 1.0;
        for (int s = 0; s < 2; ++s) {
            const double b0 = sos[s][0], b1 = sos[s][1], b2 = sos[s][2];
            const double a1 = sos[s][4], a2 = sos[s][5];
            const double B0 = b1 - a1 * b0, B1 = b2 - a2 * b0;
            const double det = 1.0 + a1 + a2;
            cf.b0[bd][s] = b0; cf.b1[bd][s] = b1; cf.b2[bd][s] = b2;
            cf.a1[bd][s] = a1; cf.a2[bd][s] = a2;
            cf.zi0[bd][s] = scale * (B0 + B1) / det;
            cf.zi1[bd][s] = scale * ((1.0 + a1) * B1 - a2 * B0) / det;
            scale *= (b0 + b1 + b2) / (1.0 + a1 + a2);
        }
    }
    return cf;
}

extern "C" void kernel_launch(void* const* d_in, const int* in_sizes, int n_in,
                              void* d_out, int out_size, void* d_ws, size_t ws_size,
                              hipStream_t stream) {
    const float* x = (const float*)d_in[0];
    float* out = (float*)d_out;
    float* Mt = (float*)d_ws;  // 2*50*50 floats = 20 KB

    const Coefs cf = make_coefs();
    build_M<<<dim3(2), dim3(64), 0, stream>>>(Mt, cf);
    filt_main<<<dim3(NC / CT), dim3(CT, NB), 0, stream>>>(x, Mt, out);
}